// Round 7
// baseline (254.726 us; speedup 1.0000x reference)
//
#include <hip/hip_runtime.h>
#include <stdint.h>

// Problem constants (fixed by setup_inputs)
#define BATCH 64
#define NPTS  131072
#define MPTS  2048
#define WORDS_PB (NPTS / 64)       // 2048 mask words per batch
#define MG_BLOCKS 2048             // 8 per CU; 32 blocks per batch
#define MG_SPAN   (NPTS / 32)      // 4096 contiguous points per block
#define MG_ITERS  (MG_SPAN / 256)  // 16

// ---------------- Threefry-2x32-20, exactly as jax/_src/prng.py ----------------
struct U2 { uint32_t a, b; };

__host__ __device__ constexpr U2 tf2x32(uint32_t k0, uint32_t k1, uint32_t x0, uint32_t x1) {
  uint32_t ks0 = k0, ks1 = k1, ks2 = k0 ^ k1 ^ 0x1BD11BDAu;
  x0 += ks0; x1 += ks1;
  const int rotA[4] = {13, 15, 26, 6};
  const int rotB[4] = {17, 29, 16, 24};
  for (int r = 0; r < 4; ++r) { x0 += x1; x1 = (x1 << rotA[r]) | (x1 >> (32 - rotA[r])); x1 ^= x0; }
  x0 += ks1; x1 += ks2 + 1u;
  for (int r = 0; r < 4; ++r) { x0 += x1; x1 = (x1 << rotB[r]) | (x1 >> (32 - rotB[r])); x1 ^= x0; }
  x0 += ks2; x1 += ks0 + 2u;
  for (int r = 0; r < 4; ++r) { x0 += x1; x1 = (x1 << rotA[r]) | (x1 >> (32 - rotA[r])); x1 ^= x0; }
  x0 += ks0; x1 += ks1 + 3u;
  for (int r = 0; r < 4; ++r) { x0 += x1; x1 = (x1 << rotB[r]) | (x1 >> (32 - rotB[r])); x1 ^= x0; }
  x0 += ks1; x1 += ks2 + 4u;
  for (int r = 0; r < 4; ++r) { x0 += x1; x1 = (x1 << rotA[r]) | (x1 >> (32 - rotA[r])); x1 ^= x0; }
  x0 += ks2; x1 += ks0 + 5u;
  return U2{x0, x1};
}

// ---------------- maskgen: logits-only stream -> mask words ----------------
// Pure two-stream read (4 B/lane, BabelStream-dot shape) + 1 store/wave/iter.
__global__ __launch_bounds__(256) void maskgen_kernel(
    const float* __restrict__ lg, unsigned long long* __restrict__ maskWords) {
  int g = blockIdx.x;
  int t = threadIdx.x;
  int lane = t & 63;
  int b = g >> 5;                            // 32 blocks per batch
  size_t base = (size_t)g * MG_SPAN;         // global point index base
  size_t inb  = base & (NPTS - 1);
  const float* l0g = lg + (size_t)b * (2 * NPTS) + inb;
  const float* l1g = l0g + NPTS;
#pragma unroll 4
  for (int k = 0; k < MG_ITERS; ++k) {
    int idx = k * 256 + t;
    bool m = l0g[idx] < l1g[idx];
    unsigned long long bal = __ballot(m);
    if (lane == 0) maskWords[(base + idx) >> 6] = bal;
  }
}

// ---------------- sumred: pc stream + mask-bit -> masked xyz sums ----------------
// Pure float4 read stream; mask word is wave-uniform (broadcast load).
__global__ __launch_bounds__(256) void sumred_kernel(
    const float4* __restrict__ pc, const unsigned long long* __restrict__ maskWords,
    float* __restrict__ sums) {
  int g = blockIdx.x;
  int t = threadIdx.x;
  int lane = t & 63, wv = t >> 6;
  int b = g >> 5;                            // 32 blocks per batch
  size_t base = (size_t)g * MG_SPAN;

  float sx = 0.f, sy = 0.f, sz = 0.f;
#pragma unroll 4
  for (int k = 0; k < MG_ITERS; ++k) {
    size_t p = base + (size_t)k * 256 + t;
    unsigned long long w = maskWords[p >> 6];   // wave-uniform -> broadcast
    float4 q = pc[p];
    if ((w >> lane) & 1ull) { sx += q.x; sy += q.y; sz += q.z; }
  }

  for (int o = 32; o; o >>= 1) {
    sx += __shfl_down(sx, o, 64);
    sy += __shfl_down(sy, o, 64);
    sz += __shfl_down(sz, o, 64);
  }
  __shared__ float ssx[4], ssy[4], ssz[4];
  if (lane == 0) { ssx[wv] = sx; ssy[wv] = sy; ssz[wv] = sz; }
  __syncthreads();
  if (t == 0) {
    atomicAdd(&sums[b * 3 + 0], ssx[0] + ssx[1] + ssx[2] + ssx[3]);
    atomicAdd(&sums[b * 3 + 1], ssy[0] + ssy[1] + ssy[2] + ssy[3]);
    atomicAdd(&sums[b * 3 + 2], ssz[0] + ssz[1] + ssz[2] + ssz[3]);
  }
}

// ---------------- Pass 2: word-level exclusive prefix + count + mean ----------------
__global__ __launch_bounds__(256) void pass2_kernel(
    const unsigned long long* __restrict__ maskWords, const float* __restrict__ sums,
    uint32_t* __restrict__ wordOff, int* __restrict__ cnt,
    float* __restrict__ mean, float* __restrict__ out) {
  int b = blockIdx.x, t = threadIdx.x;
  int lane = t & 63, wv = t >> 6;
  const unsigned long long* mw = maskWords + (size_t)b * WORDS_PB;
  int base = t * 8;
  int p[8];
  int local = 0;
#pragma unroll
  for (int k = 0; k < 8; ++k) { p[k] = __popcll(mw[base + k]); local += p[k]; }

  int x = local;
#pragma unroll
  for (int o = 1; o < 64; o <<= 1) {
    int y = __shfl_up(x, o, 64);
    if (lane >= o) x += y;
  }
  __shared__ int wsum[4];
  if (lane == 63) wsum[wv] = x;
  __syncthreads();
  int add = 0;
#pragma unroll
  for (int u = 0; u < 4; ++u) add += (u < wv) ? wsum[u] : 0;
  int run = add + x - local;
  uint32_t* wo = wordOff + (size_t)b * WORDS_PB;
#pragma unroll
  for (int k = 0; k < 8; ++k) { wo[base + k] = (uint32_t)run; run += p[k]; }

  if (t == 0) {
    int ct = wsum[0] + wsum[1] + wsum[2] + wsum[3];
    cnt[b] = ct;
    float d  = fmaxf((float)ct, 1.0f);
    float mx = sums[b * 3 + 0] / d;
    float my = sums[b * 3 + 1] / d;
    float mz = sums[b * 3 + 2] / d;
    mean[b * 3 + 0] = mx; mean[b * 3 + 1] = my; mean[b * 3 + 2] = mz;
    float* om = out + (size_t)BATCH * MPTS * 3 + (size_t)b * 3;
    om[0] = mx; om[1] = my; om[2] = mz;
  }
}

// ---------------- Pass 3: threefry randint + rank-select + gather ----------------
__global__ __launch_bounds__(256) void pass3_kernel(
    const float4* __restrict__ pc, const int* __restrict__ cnt,
    const float* __restrict__ mean, const uint32_t* __restrict__ wordOff,
    const unsigned long long* __restrict__ maskWords,
    float* __restrict__ out) {
  int blk = blockIdx.x;
  int b = blk >> 3;                        // 8 blocks per batch (2048/256)
  int t = threadIdx.x;
  int j = (blk & 7) * 256 + t;
  int gid = b * MPTS + j;

  __shared__ uint32_t sOff[WORDS_PB];
  __shared__ float sMean[3];
  __shared__ int sCnt;
  const uint32_t* wo = wordOff + (size_t)b * WORDS_PB;
#pragma unroll
  for (int k = 0; k < 8; ++k) sOff[t + k * 256] = wo[t + k * 256];
  if (t < 3)  sMean[t] = mean[b * 3 + t];
  if (t == 0) sCnt = cnt[b];
  __syncthreads();

  int cb = sCnt;
  float ox, oy, oz;
  if (cb == 0) {
    ox = oy = oz = (float)b;
  } else {
    constexpr U2 K1 = tf2x32(0u, 42u, 0u, 0u);   // split(key)[0]
    constexpr U2 K2 = tf2x32(0u, 42u, 0u, 1u);   // split(key)[1]
    uint32_t span = (uint32_t)cb;
    U2 h = tf2x32(K1.a, K1.b, 0u, (uint32_t)gid);
    U2 l = tf2x32(K2.a, K2.b, 0u, (uint32_t)gid);
    uint32_t hb = h.a ^ h.b;
    uint32_t lb = l.a ^ l.b;
    uint32_t mul = 65536u % span;
    mul = (mul * mul) % span;
    uint32_t off = ((hb % span) * mul + (lb % span)) % span;
    int r = (j < cb && cb <= MPTS) ? j : (int)off;

    int lo = 0;
#pragma unroll
    for (int step = 1024; step; step >>= 1) {
      int nxt = lo + step;
      if (nxt < WORDS_PB && sOff[nxt] <= (uint32_t)r) lo = nxt;
    }
    int rem = r - (int)sOff[lo];
    unsigned long long w = maskWords[(size_t)b * WORDS_PB + lo];

    uint32_t cur = (uint32_t)w;
    int bitbase = 0;
    int c = __popc(cur);
    if (rem >= c) { rem -= c; cur = (uint32_t)(w >> 32); bitbase = 32; }
    c = __popc(cur & 0xFFFFu); if (rem >= c) { rem -= c; cur >>= 16; bitbase += 16; }
    c = __popc(cur & 0xFFu);   if (rem >= c) { rem -= c; cur >>= 8;  bitbase += 8;  }
    c = __popc(cur & 0xFu);    if (rem >= c) { rem -= c; cur >>= 4;  bitbase += 4;  }
    c = __popc(cur & 0x3u);    if (rem >= c) { rem -= c; cur >>= 2;  bitbase += 2;  }
    c = (int)(cur & 1u);       if (rem >= c) {           cur >>= 1;  bitbase += 1;  }
    int idx = lo * 64 + bitbase;

    float4 p = pc[(size_t)b * NPTS + idx];
    ox = p.x - sMean[0]; oy = p.y - sMean[1]; oz = p.z - sMean[2];
  }
  float* o = out + (size_t)gid * 3;
  o[0] = ox; o[1] = oy; o[2] = oz;
}

// ---------------- launch ----------------
extern "C" void kernel_launch(void* const* d_in, const int* in_sizes, int n_in,
                              void* d_out, int out_size, void* d_ws, size_t ws_size,
                              hipStream_t stream) {
  const float4* pc = (const float4*)d_in[0];   // (B, N, 4) float32
  const float*  lg = (const float*)d_in[1];    // (B, 2, N) float32
  float* out = (float*)d_out;                  // obj (B,M,3) then mean (B,3)

  char* w = (char*)d_ws;
  float*    sums    = (float*)(w + 0);                     // 64*3 floats (768 B)
  int*      cnt     = (int*)(w + 1024);                    // 64 ints
  float*    mean    = (float*)(w + 2048);                  // 64*3 floats
  uint32_t* wordOff = (uint32_t*)(w + 4096);               // 64*2048 u32 = 512 KiB
  unsigned long long* maskWords =
      (unsigned long long*)(w + 4096 + 524288);            // 64*2048 u64 = 1 MiB

  hipMemsetAsync(sums, 0, 768, stream);  // ws is poisoned 0xAA; sums accumulates

  maskgen_kernel<<<MG_BLOCKS, 256, 0, stream>>>(lg, maskWords);
  sumred_kernel<<<MG_BLOCKS, 256, 0, stream>>>(pc, maskWords, sums);
  pass2_kernel<<<BATCH, 256, 0, stream>>>(maskWords, sums, wordOff, cnt, mean, out);
  pass3_kernel<<<(BATCH * MPTS) / 256, 256, 0, stream>>>(pc, cnt, mean, wordOff, maskWords, out);
}